// Round 16
// baseline (140.406 us; speedup 1.0000x reference)
//
#include <hip/hip_runtime.h>
#include <hip/hip_bf16.h>
#include <string.h>

#define IN_DIM 256
#define HC 128      // H*C = 4*32
#define HH 4
#define NEG_SLOPE 0.2f
#define BKT 64      // dst nodes per bucket
#define NBMAX 1024  // >= nbtot (939)
#define CAPB 2048   // record slots per bucket region (mean 1088, 30-sigma margin)

typedef __attribute__((ext_vector_type(8))) short bf16x8;
typedef __attribute__((ext_vector_type(4))) float f32x4;

// hardware RNE conversions (v_cvt_pk_bf16_f32); memcpy-reinterpret (bit_cast
// rejects __hip_bfloat162: not trivially copyable)
__device__ __forceinline__ unsigned short f2b(float f) {
    __hip_bfloat16 h = __float2bfloat16(f);
    unsigned short u;
    memcpy(&u, &h, 2);
    return u;
}
__device__ __forceinline__ unsigned int pk2(float a, float b) {
    float2 t; t.x = a; t.y = b;
    __hip_bfloat162 p = __float22bfloat162_rn(t);
    unsigned int u;
    memcpy(&u, &p, 4);
    return u;
}
__device__ __forceinline__ bf16x8 cvt8(const float4 lo, const float4 hi) {
    union { unsigned int u[4]; bf16x8 v; } r;
    r.u[0] = pk2(lo.x, lo.y); r.u[1] = pk2(lo.z, lo.w);
    r.u[2] = pk2(hi.x, hi.y); r.u[3] = pk2(hi.z, hi.w);
    return r.v;
}
__device__ __forceinline__ float b2f(unsigned short u) {
    return __uint_as_float(((unsigned int)u) << 16);
}

// ---- prep: W -> Wt (bf16, [col][k]) ----
__global__ void prep_kernel(const float* __restrict__ W1, const float* __restrict__ W2,
                            unsigned short* __restrict__ Wt1, unsigned short* __restrict__ Wt2) {
    const float* W = blockIdx.x ? W2 : W1;
    unsigned short* Wt = blockIdx.x ? Wt2 : Wt1;
    for (int idx = threadIdx.x; idx < HC * IN_DIM; idx += 256) {
        int c = idx >> 8, k = idx & 255;
        Wt[idx] = f2b(W[k * HC + c]);
    }
}

// ---- gemm body: 256 threads = 4 waves, 16 rows/wave (64 rows/block).
//      939-block grid -> 3.7 blocks/CU (vs 1.8 at 128 rows) ----
__device__ __forceinline__ void gemm_body(int blk, int tid,
                                          const float* __restrict__ x,
                                          const unsigned short* __restrict__ Wt,
                                          const float* __restrict__ attS,
                                          const float* __restrict__ attD,
                                          unsigned short* __restrict__ hb,
                                          float* __restrict__ asrc,
                                          float* __restrict__ adst, int N) {
    const int lane = tid & 63;
    const int wid = tid >> 6;                 // 0..3
    const int lr = lane & 15, lg = lane >> 4;
    const int r0 = blk * 64 + wid * 16;
    int ra = r0 + lr; if (ra > N - 1) ra = N - 1;
    const float* A = x + (size_t)ra * IN_DIM + lg * 8;
    const unsigned short* B0 = Wt + (size_t)lr * IN_DIM + lg * 8;

    f32x4 acc[8];
#pragma unroll
    for (int t = 0; t < 8; ++t) acc[t] = (f32x4){0.f, 0.f, 0.f, 0.f};

#pragma unroll
    for (int k0 = 0; k0 < IN_DIM; k0 += 32) {
        float4 al = *(const float4*)(A + k0);
        float4 ah = *(const float4*)(A + k0 + 4);
        bf16x8 a = cvt8(al, ah);
#pragma unroll
        for (int t = 0; t < 8; ++t) {
            bf16x8 b = *(const bf16x8*)(B0 + t * 16 * IN_DIM + k0);
            acc[t] = __builtin_amdgcn_mfma_f32_16x16x32_bf16(a, b, acc[t], 0, 0, 0);
        }
    }

    float attS_r[8], attD_r[8];
#pragma unroll
    for (int t = 0; t < 8; ++t) {
        attS_r[t] = attS[t * 16 + lr];
        attD_r[t] = attD[t * 16 + lr];
    }

    // C layout: col = t*16 + (lane&15), row = r0 + 4*(lane>>4) + i
#pragma unroll
    for (int i = 0; i < 4; ++i) {
        int row = r0 + 4 * lg + i;
        float s[4] = {0.f, 0.f, 0.f, 0.f}, dd[4] = {0.f, 0.f, 0.f, 0.f};
#pragma unroll
        for (int t = 0; t < 8; ++t) {
            float c = acc[t][i];
            s[t >> 1] += c * attS_r[t];
            dd[t >> 1] += c * attD_r[t];
        }
#pragma unroll
        for (int m = 1; m < 16; m <<= 1) {
#pragma unroll
            for (int h = 0; h < 4; ++h) {
                s[h] += __shfl_xor(s[h], m);
                dd[h] += __shfl_xor(dd[h], m);
            }
        }
        if (row < N) {
#pragma unroll
            for (int t = 0; t < 8; ++t)
                hb[(size_t)row * HC + t * 16 + lr] = f2b(acc[t][i]);
            if (lr == 0) {
#pragma unroll
                for (int h = 0; h < 4; ++h) {
                    asrc[row * HH + h] = s[h];
                    adst[row * HH + h] = dd[h];
                }
            }
        }
    }
}

// ---- MEGA: pure gemm (R12-proven structure, 64-row blocks) ----
__launch_bounds__(256)
__global__ void mega_kernel(const float* __restrict__ x1,
                            const unsigned short* __restrict__ Wt1,
                            const float* __restrict__ attS1, const float* __restrict__ attD1,
                            unsigned short* __restrict__ hb1,
                            float* __restrict__ asrc1, float* __restrict__ adst1, int N1,
                            const float* __restrict__ x2,
                            const unsigned short* __restrict__ Wt2,
                            const float* __restrict__ attS2, const float* __restrict__ attD2,
                            unsigned short* __restrict__ hb2,
                            float* __restrict__ asrc2, float* __restrict__ adst2, int N2,
                            int G1) {
    const int b = blockIdx.x;
    const int tid = threadIdx.x;
    if (b < G1) gemm_body(b, tid, x1, Wt1, attS1, attD1, hb1, asrc1, adst1, N1);
    else        gemm_body(b - G1, tid, x2, Wt2, attS2, attD2, hb2, asrc2, adst2, N2);
}

// ---- pass2 (R12-proven): single edge pass; bin into fixed 2048-slot bucket
//      regions; LDS-rank clustering + hot global cursors ----
__launch_bounds__(512)
__global__ void pass2_kernel(const int* __restrict__ ei1, int E1, int S1,
                             const int* __restrict__ ei2, int E2, int S2,
                             int nb1, int nbtot,
                             int* __restrict__ gcursor, int* __restrict__ rec) {
    __shared__ int hcnt[NBMAX];
    __shared__ int hoff[NBMAX];
    const int tid = threadIdx.x;
    for (int t = tid; t < NBMAX; t += 512) hcnt[t] = 0;
    __syncthreads();
    const int ebase = blockIdx.x * 4096;
    int myb[8], lrank[8], myrec[8];
#pragma unroll
    for (int k = 0; k < 8; ++k) {
        int i = ebase + tid + k * 512;
        int bkt = -1, src = 0, dstl = 0;
        if (i < S1) {
            int s, d;
            if (i < E1) { s = ei1[i]; d = ei1[E1 + i]; } else { s = d = i - E1; }
            bkt = d >> 6; src = s; dstl = d & 63;
        } else if (i < S1 + S2) {
            int q = i - S1, s, d;
            if (q < E2) { s = ei2[q]; d = ei2[E2 + q]; } else { s = d = q - E2; }
            bkt = nb1 + (d >> 6); src = s; dstl = d & 63;
        }
        myb[k] = bkt;
        myrec[k] = src | (dstl << 26);
        lrank[k] = (bkt >= 0) ? atomicAdd(&hcnt[bkt], 1) : 0;
    }
    __syncthreads();
    for (int t = tid; t < nbtot; t += 512)
        if (hcnt[t]) hoff[t] = atomicAdd(&gcursor[t], hcnt[t]);
    __syncthreads();
#pragma unroll
    for (int k = 0; k < 8; ++k) {
        int bkt = myb[k];
        if (bkt >= 0) {
            int pos = hoff[bkt] + lrank[k];
            if (pos < CAPB) rec[(size_t)bkt * CAPB + pos] = myrec[k];
        }
    }
}

// ---- pass3 (R12-proven): one block per bucket; LDS counting-sort (int
//      atomics) + register accumulate, pipelined random h reads; fused epilogue
__launch_bounds__(512)
__global__ void pass3_kernel(const int* __restrict__ rec, const int* __restrict__ gcursor,
                             int boff,
                             const unsigned short* __restrict__ hp,
                             const float* __restrict__ asrc, const float* __restrict__ adst,
                             const float* __restrict__ bias,
                             const int* __restrict__ ga,       // nullable
                             const float* __restrict__ other,  // nullable
                             float* __restrict__ out, int N) {
    __shared__ int srec[CAPB + 16];
    __shared__ int ncnt[BKT];
    __shared__ int nsc[BKT];
    __shared__ int ncur[BKT];
    __shared__ float adl[BKT * HH];
    const int tid = threadIdx.x;
    const int B = boff + blockIdx.x;
    const int n0 = blockIdx.x * BKT;
    int mycnt = gcursor[B];
    if (mycnt > CAPB) mycnt = CAPB;
    const int base = B * CAPB;

    for (int t = tid; t < BKT * HH; t += 512) {
        int node = n0 + (t >> 2);
        adl[t] = (node < N) ? adst[node * HH + (t & 3)] : 0.f;
    }
    if (tid < BKT) { ncnt[tid] = 0; ncur[tid] = 0; }
    __syncthreads();
    // histogram by local dst
    for (int t = tid; t < mycnt; t += 512)
        atomicAdd(&ncnt[(rec[base + t] >> 26) & 63], 1);
    __syncthreads();
    // inclusive scan of ncnt (single wave, shfl)
    if (tid < 64) {
        int v = ncnt[tid];
#pragma unroll
        for (int off = 1; off < 64; off <<= 1) {
            int u = __shfl_up(v, off);
            if (tid >= off) v += u;
        }
        nsc[tid] = v;
    }
    if (tid < 16) srec[mycnt + tid] = 0;   // zero pad for pipelined reads
    __syncthreads();
    // counting-sort scatter into srec
    for (int t = tid; t < mycnt; t += 512) {
        int r = rec[base + t];
        int dl = (r >> 26) & 63;
        int pos = nsc[dl] - ncnt[dl] + atomicAdd(&ncur[dl], 1);
        srec[pos] = r;
    }
    __syncthreads();

    const int slot = tid >> 5;       // 0..15
    const int j = tid & 31;
    const int head = j >> 3;
    const unsigned short* hbj = hp + 4 * j;

    // accumulate: slot handles local nodes slot, slot+16, slot+32, slot+48
#pragma unroll
    for (int nl = 0; nl < 4; ++nl) {
        const int nloc = slot + (nl << 4);
        const int len = ncnt[nloc];
        float4 acc = {0.f, 0.f, 0.f, 0.f};
        float ws = 0.f;
        if (len > 0) {
            const int s0 = nsc[nloc] - len;
            const float adv = adl[nloc * HH + head];
            int rC[4], rN[4];
            float aC[4];
            ushort4 hC[4];
#pragma unroll
            for (int k = 0; k < 4; ++k) rC[k] = srec[s0 + k];
#pragma unroll
            for (int k = 0; k < 4; ++k) {
                int s = rC[k] & 0x3FFFFFF;
                aC[k] = asrc[s * HH + head];
                hC[k] = *(const ushort4*)(hbj + (size_t)s * HC);
            }
#pragma unroll
            for (int k = 0; k < 4; ++k) rN[k] = srec[s0 + 4 + k];
            for (int e = 0; e < len; e += 4) {
#pragma unroll
                for (int k = 0; k < 4; ++k) {
                    float alpha = aC[k] + adv;
                    alpha = alpha > 0.f ? alpha : NEG_SLOPE * alpha;
                    float w = (e + k < len) ? __expf(alpha) : 0.f;
                    acc.x += w * b2f(hC[k].x);
                    acc.y += w * b2f(hC[k].y);
                    acc.z += w * b2f(hC[k].z);
                    acc.w += w * b2f(hC[k].w);
                    ws += w;
                }
#pragma unroll
                for (int k = 0; k < 4; ++k) rC[k] = rN[k];
#pragma unroll
                for (int k = 0; k < 4; ++k) {
                    int s = rC[k] & 0x3FFFFFF;
                    aC[k] = asrc[s * HH + head];
                    hC[k] = *(const ushort4*)(hbj + (size_t)s * HC);
                }
#pragma unroll
                for (int k = 0; k < 4; ++k) rN[k] = srec[s0 + e + 8 + k];
            }
        }
        // epilogue for this node: normalize + bias (+ grouped add)
        int node = n0 + nloc;
        if (node < N) {
            float inv = 1.f / ws;
            const float4 bb = *(const float4*)(bias + 4 * j);
            float4 o = {acc.x * inv + bb.x, acc.y * inv + bb.y,
                        acc.z * inv + bb.z, acc.w * inv + bb.w};
            if (ga) {
                const float4 ov = *(const float4*)(other + (size_t)ga[node] * HC + 4 * j);
                o.x += ov.x; o.y += ov.y; o.z += ov.z; o.w += ov.w;
            }
            *(float4*)(out + (size_t)node * HC + 4 * j) = o;
        }
    }
}

extern "C" void kernel_launch(void* const* d_in, const int* in_sizes, int n_in,
                              void* d_out, int out_size, void* d_ws, size_t ws_size,
                              hipStream_t stream) {
    const float* x1  = (const float*)d_in[0];
    const int*   ei1 = (const int*)d_in[1];
    const float* x2  = (const float*)d_in[2];
    const int*   ei2 = (const int*)d_in[3];
    const int*   ga  = (const int*)d_in[4];
    const float* W1    = (const float*)d_in[5];
    const float* attS1 = (const float*)d_in[6];
    const float* attD1 = (const float*)d_in[7];
    const float* b1    = (const float*)d_in[8];
    const float* W2    = (const float*)d_in[9];
    const float* attS2 = (const float*)d_in[10];
    const float* attD2 = (const float*)d_in[11];
    const float* b2    = (const float*)d_in[12];

    const int N1 = in_sizes[0] / IN_DIM;
    const int E1 = in_sizes[1] / 2;
    const int N2 = in_sizes[2] / IN_DIM;
    const int E2 = in_sizes[3] / 2;
    const int S1 = E1 + N1, S2 = E2 + N2;
    const int nb1 = (N1 + BKT - 1) / BKT;   // 782
    const int nb2 = (N2 + BKT - 1) / BKT;   // 157
    const int nbtot = nb1 + nb2;            // 939

    // ---- workspace layout ----
    char* p = (char*)d_ws;
    auto alloc = [&](size_t bytes) {
        char* r = p; p += (bytes + 511) & ~(size_t)511; return r;
    };
    unsigned short* hb1 = (unsigned short*)alloc((size_t)N1 * HC * 2);
    unsigned short* hb2 = (unsigned short*)alloc((size_t)N2 * HC * 2);
    unsigned short* Wt1 = (unsigned short*)alloc((size_t)IN_DIM * HC * 2);
    unsigned short* Wt2 = (unsigned short*)alloc((size_t)IN_DIM * HC * 2);
    float* asrc1 = (float*)alloc((size_t)N1 * HH * 4);
    float* adst1 = (float*)alloc((size_t)N1 * HH * 4);
    float* asrc2 = (float*)alloc((size_t)N2 * HH * 4);
    float* adst2 = (float*)alloc((size_t)N2 * HH * 4);
    int* gcursor = (int*)alloc(NBMAX * 4);
    int* rec     = (int*)alloc((size_t)nbtot * CAPB * 4);   // 7.7 MB

    float* out1 = (float*)d_out;
    float* out2 = (float*)d_out + (size_t)N1 * HC;

    (void)hipMemsetAsync(gcursor, 0, NBMAX * 4, stream);

    prep_kernel<<<2, 256, 0, stream>>>(W1, W2, Wt1, Wt2);

    // MEGA: gemm1|gemm2 (64 rows/block -> 939 blocks, 3.7/CU)
    const int G1 = (N1 + 63) / 64, G2 = (N2 + 63) / 64;   // 782, 157
    mega_kernel<<<G1 + G2, 256, 0, stream>>>(
        x1, Wt1, attS1, attD1, hb1, asrc1, adst1, N1,
        x2, Wt2, attS2, attD2, hb2, asrc2, adst2, N2, G1);

    // single edge pass: bin into fixed-capacity bucket regions
    const int GP = (S1 + S2 + 4095) / 4096;
    pass2_kernel<<<GP, 512, 0, stream>>>(ei1, E1, S1, ei2, E2, S2,
                                         nb1, nbtot, gcursor, rec);

    // graph2 buckets first (graph1 epilogue gathers out2 through ga)
    pass3_kernel<<<nb2, 512, 0, stream>>>(rec, gcursor, nb1, hb2, asrc2, adst2,
                                          b2, nullptr, nullptr, out2, N2);
    pass3_kernel<<<nb1, 512, 0, stream>>>(rec, gcursor, 0, hb1, asrc1, adst1,
                                          b1, ga, out2, out1, N1);
}

// Round 17
// 125.739 us; speedup vs baseline: 1.1166x; 1.1166x over previous
//
#include <hip/hip_runtime.h>
#include <hip/hip_bf16.h>
#include <string.h>

#define IN_DIM 256
#define HC 128      // H*C = 4*32
#define HH 4
#define NEG_SLOPE 0.2f
#define BKT 64      // dst nodes per bucket
#define NBMAX 1024  // >= nbtot (939)
#define CAPB 2048   // record slots per bucket region (mean 1088, 30-sigma margin)

typedef __attribute__((ext_vector_type(8))) short bf16x8;
typedef __attribute__((ext_vector_type(4))) float f32x4;

// hardware RNE conversions (v_cvt_pk_bf16_f32); memcpy-reinterpret (bit_cast
// rejects __hip_bfloat162: not trivially copyable)
__device__ __forceinline__ unsigned short f2b(float f) {
    __hip_bfloat16 h = __float2bfloat16(f);
    unsigned short u;
    memcpy(&u, &h, 2);
    return u;
}
__device__ __forceinline__ unsigned int pk2(float a, float b) {
    float2 t; t.x = a; t.y = b;
    __hip_bfloat162 p = __float22bfloat162_rn(t);
    unsigned int u;
    memcpy(&u, &p, 4);
    return u;
}
__device__ __forceinline__ bf16x8 cvt8(const float4 lo, const float4 hi) {
    union { unsigned int u[4]; bf16x8 v; } r;
    r.u[0] = pk2(lo.x, lo.y); r.u[1] = pk2(lo.z, lo.w);
    r.u[2] = pk2(hi.x, hi.y); r.u[3] = pk2(hi.z, hi.w);
    return r.v;
}
__device__ __forceinline__ float b2f(unsigned short u) {
    return __uint_as_float(((unsigned int)u) << 16);
}

// ---- prep: W -> Wt (bf16, [col][k]); block 0 also zeroes gcursor ----
__global__ void prep_kernel(const float* __restrict__ W1, const float* __restrict__ W2,
                            unsigned short* __restrict__ Wt1, unsigned short* __restrict__ Wt2,
                            int* __restrict__ gcursor) {
    const float* W = blockIdx.x ? W2 : W1;
    unsigned short* Wt = blockIdx.x ? Wt2 : Wt1;
    if (blockIdx.x == 0) {
        for (int t = threadIdx.x; t < NBMAX; t += 256) gcursor[t] = 0;
    }
    for (int idx = threadIdx.x; idx < HC * IN_DIM; idx += 256) {
        int c = idx >> 8, k = idx & 255;
        Wt[idx] = f2b(W[k * HC + c]);
    }
}

// ---- gemm body: 256 threads = 4 waves, 32 rows/wave (128 rows/block).
//      acc[2][8]: 2 MFMAs per B-fragment load (proven best config, R12) ----
__device__ __forceinline__ void gemm_body(int blk, int tid,
                                          const float* __restrict__ x,
                                          const unsigned short* __restrict__ Wt,
                                          const float* __restrict__ attS,
                                          const float* __restrict__ attD,
                                          unsigned short* __restrict__ hb,
                                          float* __restrict__ asrc,
                                          float* __restrict__ adst, int N) {
    const int lane = tid & 63;
    const int wid = tid >> 6;
    const int lr = lane & 15, lg = lane >> 4;
    const int r0 = blk * 128 + wid * 32;
    int ra0 = r0 + lr;      if (ra0 > N - 1) ra0 = N - 1;
    int ra1 = r0 + 16 + lr; if (ra1 > N - 1) ra1 = N - 1;
    const float* A0 = x + (size_t)ra0 * IN_DIM + lg * 8;
    const float* A1 = x + (size_t)ra1 * IN_DIM + lg * 8;
    const unsigned short* B0 = Wt + (size_t)lr * IN_DIM + lg * 8;

    f32x4 acc[2][8];
#pragma unroll
    for (int h = 0; h < 2; ++h)
#pragma unroll
        for (int t = 0; t < 8; ++t) acc[h][t] = (f32x4){0.f, 0.f, 0.f, 0.f};

#pragma unroll
    for (int k0 = 0; k0 < IN_DIM; k0 += 32) {
        float4 a0l = *(const float4*)(A0 + k0);
        float4 a0h = *(const float4*)(A0 + k0 + 4);
        float4 a1l = *(const float4*)(A1 + k0);
        float4 a1h = *(const float4*)(A1 + k0 + 4);
        bf16x8 a0 = cvt8(a0l, a0h);
        bf16x8 a1 = cvt8(a1l, a1h);
#pragma unroll
        for (int t = 0; t < 8; ++t) {
            bf16x8 b = *(const bf16x8*)(B0 + t * 16 * IN_DIM + k0);
            acc[0][t] = __builtin_amdgcn_mfma_f32_16x16x32_bf16(a0, b, acc[0][t], 0, 0, 0);
            acc[1][t] = __builtin_amdgcn_mfma_f32_16x16x32_bf16(a1, b, acc[1][t], 0, 0, 0);
        }
    }

    float attS_r[8], attD_r[8];
#pragma unroll
    for (int t = 0; t < 8; ++t) {
        attS_r[t] = attS[t * 16 + lr];
        attD_r[t] = attD[t * 16 + lr];
    }

    // C layout: col = t*16 + (lane&15), row = r0 + half*16 + 4*(lane>>4) + i
#pragma unroll
    for (int half = 0; half < 2; ++half) {
#pragma unroll
        for (int i = 0; i < 4; ++i) {
            int row = r0 + half * 16 + 4 * lg + i;
            float s[4] = {0.f, 0.f, 0.f, 0.f}, dd[4] = {0.f, 0.f, 0.f, 0.f};
#pragma unroll
            for (int t = 0; t < 8; ++t) {
                float c = acc[half][t][i];
                s[t >> 1] += c * attS_r[t];
                dd[t >> 1] += c * attD_r[t];
            }
#pragma unroll
            for (int m = 1; m < 16; m <<= 1) {
#pragma unroll
                for (int h = 0; h < 4; ++h) {
                    s[h] += __shfl_xor(s[h], m);
                    dd[h] += __shfl_xor(dd[h], m);
                }
            }
            if (row < N) {
#pragma unroll
                for (int t = 0; t < 8; ++t)
                    hb[(size_t)row * HC + t * 16 + lr] = f2b(acc[half][t][i]);
                if (lr == 0) {
#pragma unroll
                    for (int h = 0; h < 4; ++h) {
                        asrc[row * HH + h] = s[h];
                        adst[row * HH + h] = dd[h];
                    }
                }
            }
        }
    }
}

// ---- MEGA: pure gemm (R12-proven structure, 128-row blocks) ----
__launch_bounds__(256)
__global__ void mega_kernel(const float* __restrict__ x1,
                            const unsigned short* __restrict__ Wt1,
                            const float* __restrict__ attS1, const float* __restrict__ attD1,
                            unsigned short* __restrict__ hb1,
                            float* __restrict__ asrc1, float* __restrict__ adst1, int N1,
                            const float* __restrict__ x2,
                            const unsigned short* __restrict__ Wt2,
                            const float* __restrict__ attS2, const float* __restrict__ attD2,
                            unsigned short* __restrict__ hb2,
                            float* __restrict__ asrc2, float* __restrict__ adst2, int N2,
                            int G1) {
    const int b = blockIdx.x;
    const int tid = threadIdx.x;
    if (b < G1) gemm_body(b, tid, x1, Wt1, attS1, attD1, hb1, asrc1, adst1, N1);
    else        gemm_body(b - G1, tid, x2, Wt2, attS2, attD2, hb2, asrc2, adst2, N2);
}

// ---- pass2 (R12-proven): single edge pass; bin into fixed 2048-slot bucket
//      regions; LDS-rank clustering + hot global cursors ----
__launch_bounds__(512)
__global__ void pass2_kernel(const int* __restrict__ ei1, int E1, int S1,
                             const int* __restrict__ ei2, int E2, int S2,
                             int nb1, int nbtot,
                             int* __restrict__ gcursor, int* __restrict__ rec) {
    __shared__ int hcnt[NBMAX];
    __shared__ int hoff[NBMAX];
    const int tid = threadIdx.x;
    for (int t = tid; t < NBMAX; t += 512) hcnt[t] = 0;
    __syncthreads();
    const int ebase = blockIdx.x * 4096;
    int myb[8], lrank[8], myrec[8];
#pragma unroll
    for (int k = 0; k < 8; ++k) {
        int i = ebase + tid + k * 512;
        int bkt = -1, src = 0, dstl = 0;
        if (i < S1) {
            int s, d;
            if (i < E1) { s = ei1[i]; d = ei1[E1 + i]; } else { s = d = i - E1; }
            bkt = d >> 6; src = s; dstl = d & 63;
        } else if (i < S1 + S2) {
            int q = i - S1, s, d;
            if (q < E2) { s = ei2[q]; d = ei2[E2 + q]; } else { s = d = q - E2; }
            bkt = nb1 + (d >> 6); src = s; dstl = d & 63;
        }
        myb[k] = bkt;
        myrec[k] = src | (dstl << 26);
        lrank[k] = (bkt >= 0) ? atomicAdd(&hcnt[bkt], 1) : 0;
    }
    __syncthreads();
    for (int t = tid; t < nbtot; t += 512)
        if (hcnt[t]) hoff[t] = atomicAdd(&gcursor[t], hcnt[t]);
    __syncthreads();
#pragma unroll
    for (int k = 0; k < 8; ++k) {
        int bkt = myb[k];
        if (bkt >= 0) {
            int pos = hoff[bkt] + lrank[k];
            if (pos < CAPB) rec[(size_t)bkt * CAPB + pos] = myrec[k];
        }
    }
}

// ---- pass3 (R12-proven): one block per bucket; LDS counting-sort (int
//      atomics) + register accumulate, pipelined random h reads; fused epilogue
__launch_bounds__(512)
__global__ void pass3_kernel(const int* __restrict__ rec, const int* __restrict__ gcursor,
                             int boff,
                             const unsigned short* __restrict__ hp,
                             const float* __restrict__ asrc, const float* __restrict__ adst,
                             const float* __restrict__ bias,
                             const int* __restrict__ ga,       // nullable
                             const float* __restrict__ other,  // nullable
                             float* __restrict__ out, int N) {
    __shared__ int srec[CAPB + 16];
    __shared__ int ncnt[BKT];
    __shared__ int nsc[BKT];
    __shared__ int ncur[BKT];
    __shared__ float adl[BKT * HH];
    const int tid = threadIdx.x;
    const int B = boff + blockIdx.x;
    const int n0 = blockIdx.x * BKT;
    int mycnt = gcursor[B];
    if (mycnt > CAPB) mycnt = CAPB;
    const int base = B * CAPB;

    for (int t = tid; t < BKT * HH; t += 512) {
        int node = n0 + (t >> 2);
        adl[t] = (node < N) ? adst[node * HH + (t & 3)] : 0.f;
    }
    if (tid < BKT) { ncnt[tid] = 0; ncur[tid] = 0; }
    __syncthreads();
    // histogram by local dst
    for (int t = tid; t < mycnt; t += 512)
        atomicAdd(&ncnt[(rec[base + t] >> 26) & 63], 1);
    __syncthreads();
    // inclusive scan of ncnt (single wave, shfl)
    if (tid < 64) {
        int v = ncnt[tid];
#pragma unroll
        for (int off = 1; off < 64; off <<= 1) {
            int u = __shfl_up(v, off);
            if (tid >= off) v += u;
        }
        nsc[tid] = v;
    }
    if (tid < 16) srec[mycnt + tid] = 0;   // zero pad for pipelined reads
    __syncthreads();
    // counting-sort scatter into srec
    for (int t = tid; t < mycnt; t += 512) {
        int r = rec[base + t];
        int dl = (r >> 26) & 63;
        int pos = nsc[dl] - ncnt[dl] + atomicAdd(&ncur[dl], 1);
        srec[pos] = r;
    }
    __syncthreads();

    const int slot = tid >> 5;       // 0..15
    const int j = tid & 31;
    const int head = j >> 3;
    const unsigned short* hbj = hp + 4 * j;

    // accumulate: slot handles local nodes slot, slot+16, slot+32, slot+48
#pragma unroll
    for (int nl = 0; nl < 4; ++nl) {
        const int nloc = slot + (nl << 4);
        const int len = ncnt[nloc];
        float4 acc = {0.f, 0.f, 0.f, 0.f};
        float ws = 0.f;
        if (len > 0) {
            const int s0 = nsc[nloc] - len;
            const float adv = adl[nloc * HH + head];
            int rC[4], rN[4];
            float aC[4];
            ushort4 hC[4];
#pragma unroll
            for (int k = 0; k < 4; ++k) rC[k] = srec[s0 + k];
#pragma unroll
            for (int k = 0; k < 4; ++k) {
                int s = rC[k] & 0x3FFFFFF;
                aC[k] = asrc[s * HH + head];
                hC[k] = *(const ushort4*)(hbj + (size_t)s * HC);
            }
#pragma unroll
            for (int k = 0; k < 4; ++k) rN[k] = srec[s0 + 4 + k];
            for (int e = 0; e < len; e += 4) {
#pragma unroll
                for (int k = 0; k < 4; ++k) {
                    float alpha = aC[k] + adv;
                    alpha = alpha > 0.f ? alpha : NEG_SLOPE * alpha;
                    float w = (e + k < len) ? __expf(alpha) : 0.f;
                    acc.x += w * b2f(hC[k].x);
                    acc.y += w * b2f(hC[k].y);
                    acc.z += w * b2f(hC[k].z);
                    acc.w += w * b2f(hC[k].w);
                    ws += w;
                }
#pragma unroll
                for (int k = 0; k < 4; ++k) rC[k] = rN[k];
#pragma unroll
                for (int k = 0; k < 4; ++k) {
                    int s = rC[k] & 0x3FFFFFF;
                    aC[k] = asrc[s * HH + head];
                    hC[k] = *(const ushort4*)(hbj + (size_t)s * HC);
                }
#pragma unroll
                for (int k = 0; k < 4; ++k) rN[k] = srec[s0 + e + 8 + k];
            }
        }
        // epilogue for this node: normalize + bias (+ grouped add)
        int node = n0 + nloc;
        if (node < N) {
            float inv = 1.f / ws;
            const float4 bb = *(const float4*)(bias + 4 * j);
            float4 o = {acc.x * inv + bb.x, acc.y * inv + bb.y,
                        acc.z * inv + bb.z, acc.w * inv + bb.w};
            if (ga) {
                const float4 ov = *(const float4*)(other + (size_t)ga[node] * HC + 4 * j);
                o.x += ov.x; o.y += ov.y; o.z += ov.z; o.w += ov.w;
            }
            *(float4*)(out + (size_t)node * HC + 4 * j) = o;
        }
    }
}

extern "C" void kernel_launch(void* const* d_in, const int* in_sizes, int n_in,
                              void* d_out, int out_size, void* d_ws, size_t ws_size,
                              hipStream_t stream) {
    const float* x1  = (const float*)d_in[0];
    const int*   ei1 = (const int*)d_in[1];
    const float* x2  = (const float*)d_in[2];
    const int*   ei2 = (const int*)d_in[3];
    const int*   ga  = (const int*)d_in[4];
    const float* W1    = (const float*)d_in[5];
    const float* attS1 = (const float*)d_in[6];
    const float* attD1 = (const float*)d_in[7];
    const float* b1    = (const float*)d_in[8];
    const float* W2    = (const float*)d_in[9];
    const float* attS2 = (const float*)d_in[10];
    const float* attD2 = (const float*)d_in[11];
    const float* b2    = (const float*)d_in[12];

    const int N1 = in_sizes[0] / IN_DIM;
    const int E1 = in_sizes[1] / 2;
    const int N2 = in_sizes[2] / IN_DIM;
    const int E2 = in_sizes[3] / 2;
    const int S1 = E1 + N1, S2 = E2 + N2;
    const int nb1 = (N1 + BKT - 1) / BKT;   // 782
    const int nb2 = (N2 + BKT - 1) / BKT;   // 157
    const int nbtot = nb1 + nb2;            // 939

    // ---- workspace layout ----
    char* p = (char*)d_ws;
    auto alloc = [&](size_t bytes) {
        char* r = p; p += (bytes + 511) & ~(size_t)511; return r;
    };
    unsigned short* hb1 = (unsigned short*)alloc((size_t)N1 * HC * 2);
    unsigned short* hb2 = (unsigned short*)alloc((size_t)N2 * HC * 2);
    unsigned short* Wt1 = (unsigned short*)alloc((size_t)IN_DIM * HC * 2);
    unsigned short* Wt2 = (unsigned short*)alloc((size_t)IN_DIM * HC * 2);
    float* asrc1 = (float*)alloc((size_t)N1 * HH * 4);
    float* adst1 = (float*)alloc((size_t)N1 * HH * 4);
    float* asrc2 = (float*)alloc((size_t)N2 * HH * 4);
    float* adst2 = (float*)alloc((size_t)N2 * HH * 4);
    int* gcursor = (int*)alloc(NBMAX * 4);
    int* rec     = (int*)alloc((size_t)nbtot * CAPB * 4);   // 7.7 MB

    float* out1 = (float*)d_out;
    float* out2 = (float*)d_out + (size_t)N1 * HC;

    // prep also zeroes gcursor (block 0) -> no separate memset dispatch
    prep_kernel<<<2, 256, 0, stream>>>(W1, W2, Wt1, Wt2, gcursor);

    // MEGA: gemm1|gemm2 (128 rows/block, acc[2][8] — proven best)
    const int G1 = (N1 + 127) / 128, G2 = (N2 + 127) / 128;   // 391, 79
    mega_kernel<<<G1 + G2, 256, 0, stream>>>(
        x1, Wt1, attS1, attD1, hb1, asrc1, adst1, N1,
        x2, Wt2, attS2, attD2, hb2, asrc2, adst2, N2, G1);

    // single edge pass: bin into fixed-capacity bucket regions
    const int GP = (S1 + S2 + 4095) / 4096;
    pass2_kernel<<<GP, 512, 0, stream>>>(ei1, E1, S1, ei2, E2, S2,
                                         nb1, nbtot, gcursor, rec);

    // graph2 buckets first (graph1 epilogue gathers out2 through ga)
    pass3_kernel<<<nb2, 512, 0, stream>>>(rec, gcursor, nb1, hb2, asrc2, adst2,
                                          b2, nullptr, nullptr, out2, N2);
    pass3_kernel<<<nb1, 512, 0, stream>>>(rec, gcursor, 0, hb1, asrc1, adst1,
                                          b1, ga, out2, out1, N1);
}